// Round 6
// baseline (32973.331 us; speedup 1.0000x reference)
//
#include <hip/hip_runtime.h>

typedef __bf16 bf16;
typedef __bf16 bf16x8 __attribute__((ext_vector_type(8)));
typedef __bf16 bf16x4 __attribute__((ext_vector_type(4)));
typedef float f32x4 __attribute__((ext_vector_type(4)));
typedef unsigned long long u64;

#define SCOPE_AGENT __HIP_MEMORY_SCOPE_AGENT

// B=32, T=256, H=1024, HY=256, E=64, L=2
// d_out = h_seq (32,256,1024) ++ h_last (32,1024) ++ c_last (32,1024), fp32

__device__ __forceinline__ float sigf(float x) { return 1.0f / (1.0f + __expf(-x)); }
__device__ __forceinline__ float tanhf_fast(float x) {
  float e = __expf(-2.0f * fabsf(x));
  float r = (1.0f - e) / (1.0f + e);
  return copysignf(r, x);
}
__device__ __forceinline__ f32x4 mfma16(bf16x8 a, bf16x8 b, f32x4 c) {
  return __builtin_amdgcn_mfma_f32_16x16x32_bf16(a, b, c, 0, 0, 0);
}
__device__ __forceinline__ u64 uld(const u64* p) { return __hip_atomic_load(p, __ATOMIC_RELAXED, SCOPE_AGENT); }
__device__ __forceinline__ void ust(u64* p, u64 v) { __hip_atomic_store(p, v, __ATOMIC_RELAXED, SCOPE_AGENT); }
__device__ __forceinline__ int ildi(const int* p) { return __hip_atomic_load(p, __ATOMIC_RELAXED, SCOPE_AGENT); }
__device__ __forceinline__ void isti(int* p, int v) { __hip_atomic_store(p, v, __ATOMIC_RELAXED, SCOPE_AGENT); }

// ---------------- dtype detector ----------------
__global__ void detect_kernel(const void* probe, int* flag) {
  __shared__ int cnt;
  if (threadIdx.x == 0) cnt = 0;
  __syncthreads();
  const bf16* p = (const bf16*)probe;
  int local = 0;
  for (int j = threadIdx.x; j < 8192; j += 256) {
    float x = (float)p[j];
    bool wild = (x != x) || (fabsf(x) > 1e3f) || (x != 0.0f && fabsf(x) < 1e-30f);
    local += wild ? 1 : 0;
  }
  atomicAdd(&cnt, local);
  __syncthreads();
  if (threadIdx.x == 0) *flag = (cnt > 64) ? 1 : 0;
}

// ---------------- convert 15 tensors to canonical bf16 ----------------
struct CvtSrc { const void* s[15]; };
struct CvtDst { bf16* d[15]; };

__global__ __launch_bounds__(256) void convert_kernel(CvtSrc S, CvtDst D, const int* flag) {
  const int pre[16] = {0, 8388608, 16777216, 25165824, 29360128, 29884416, 29886464,
                       30017536, 30018048, 30149120, 30149632, 30280704, 30804992,
                       31329280, 31853568, 31861760};
  const int fp32 = *flag;
  const int nvec = 31861760 / 4;
  for (int v = blockIdx.x * 256 + threadIdx.x; v < nvec; v += gridDim.x * 256) {
    int e = v * 4;
    int seg = 0;
#pragma unroll
    for (int k = 1; k < 15; ++k) seg += (e >= pre[k]) ? 1 : 0;
    int off = e - pre[seg];
    bf16* d = D.d[seg] + off;
    if (fp32) {
      const float* s = (const float*)S.s[seg] + off;
      float4 x = *(const float4*)s;
      d[0] = (bf16)x.x; d[1] = (bf16)x.y; d[2] = (bf16)x.z; d[3] = (bf16)x.w;
    } else {
      const bf16* s = (const bf16*)S.s[seg] + off;
      d[0] = s[0]; d[1] = s[1]; d[2] = s[2]; d[3] = s[3];
    }
  }
}

// ---------------- init: zero h/hh publish buffers + flags/counters ----------------
__global__ void init_kernel(u64* hpub, u64* hhpub, int* flags) {
  int i = blockIdx.x * 256 + threadIdx.x;   // 32 blocks -> 8192 threads
  hpub[i] = 0ull;                           // 32*256 u64
  if (i < 2048) hhpub[i] = 0ull;            // 32*64 u64
  if (i < 4096) flags[i] = 0;
}

// ---------------- precompute GEMM (verified) ----------------
__global__ __launch_bounds__(256) void gemm_pre(
    const bf16* __restrict__ A, const bf16* __restrict__ w_ih_l,
    const bf16* __restrict__ hwih_l, bf16* __restrict__ Xp, float* __restrict__ Hxp) {
  constexpr int LDT = 72;
  __shared__ alignas(16) bf16 As[64 * LDT];
  __shared__ alignas(16) bf16 Bs[64 * LDT];
  const int bm = blockIdx.x & 127;
  const int bn = blockIdx.x >> 7;
  const int m0 = bm * 64, n0 = bn * 64;
  const int tid = threadIdx.x;
  const int lane = tid & 63, wid = tid >> 6;
  const int l15 = lane & 15, q = lane >> 4;
  const int srow = tid >> 2, sk = (tid & 3) * 16;
  const bf16* arow = A + (size_t)(m0 + srow) * 1024;
  const int n = n0 + srow;
  const bf16* brow = (n < 4096) ? (w_ih_l + (size_t)n * 1024)
                                : (hwih_l + (size_t)(n - 4096) * 2048);
  f32x4 acc[4] = {};
  for (int kb = 0; kb < 1024; kb += 64) {
    *(bf16x8*)(&As[srow * LDT + sk])     = *(const bf16x8*)(arow + kb + sk);
    *(bf16x8*)(&As[srow * LDT + sk + 8]) = *(const bf16x8*)(arow + kb + sk + 8);
    *(bf16x8*)(&Bs[srow * LDT + sk])     = *(const bf16x8*)(brow + kb + sk);
    *(bf16x8*)(&Bs[srow * LDT + sk + 8]) = *(const bf16x8*)(brow + kb + sk + 8);
    __syncthreads();
#pragma unroll
    for (int kk = 0; kk < 64; kk += 32) {
      bf16x8 av = *(const bf16x8*)(&As[(wid * 16 + l15) * LDT + kk + q * 8]);
#pragma unroll
      for (int j = 0; j < 4; ++j) {
        bf16x8 bv = *(const bf16x8*)(&Bs[(j * 16 + l15) * LDT + kk + q * 8]);
        acc[j] = mfma16(av, bv, acc[j]);
      }
    }
    __syncthreads();
  }
#pragma unroll
  for (int j = 0; j < 4; ++j) {
    const int gn = n0 + j * 16 + l15;
#pragma unroll
    for (int r = 0; r < 4; ++r) {
      const int gm = m0 + wid * 16 + q * 4 + r;
      float v = acc[j][r];
      if (gn < 4096) Xp[(size_t)gm * 4096 + gn] = (bf16)v;
      else           Hxp[(size_t)gm * 1024 + (gn - 4096)] = v;
    }
  }
}

struct SeqArgs {
  int layer;
  const bf16 *w_hh, *hwih, *hwhh, *hyb;
  const bf16 *w_zh, *b_zh, *w_zx, *b_zx, *w_zb;
  const bf16 *w_dh, *w_dx, *w_db, *b0;
  const bf16 *Xp; const float *Hxp;
  u64 *hpub, *hhpub;
  bf16 *Y0; float *outp;
  int *flags;
};

// ---------------- persistent sequential kernel: 256 steps of one layer --------------
// 8 INDEPENDENT groups of 16 blocks (group = batch-quad bq). No global barrier.
// Per step, per group: sync A = h exchange; sync B = hh2 exchange. Each sync is one
// fetch_add counter + one generation line -> 16 pollers/line, 1 lane/block polling.
// hc (hyper cell state) is block-private (each block owns 16 of 256 hyper dims).
__global__ __launch_bounds__(256) void seq_kernel(SeqArgs a) {
  __shared__ alignas(16) bf16 hA4[4][1032];    // h(t), own 4 batches, full 1024
  __shared__ alignas(16) bf16 hh2A[4][264];    // hh2: holds (t-1) for hg, then (t) for z
  __shared__ alignas(16) float hgs4[4][4][16]; // [gate][b][dL]
  __shared__ alignas(16) bf16 hh2tmp[4][16];
  __shared__ alignas(16) float RhL[4][256];
  __shared__ alignas(16) float zsL[4][768];
  __shared__ alignas(16) float presL[4][256];
  __shared__ alignas(16) bf16 hbuf[4][64];

  const int tid = threadIdx.x;
  const int lane = tid & 63, wid = tid >> 6;   // wid = gate g
  const int l15 = lane & 15, q = lane >> 4;
  const int blk = blockIdx.x;
  const int bq = blk >> 4, s16 = blk & 15;     // group, h/dim-slice
  const int layer = a.layer;
  const bf16* whh_l  = a.w_hh + (size_t)layer * 4096 * 1024;
  const bf16* hwih_l = a.hwih + (size_t)layer * 1024 * 2048;
  const bf16* hwhh_l = a.hwhh + (size_t)layer * 1024 * 256;
  const bf16* hybl   = a.hyb + (size_t)layer * 1024;
  const bf16* b0_l   = a.b0 + (size_t)layer * 4096;
  int* genA = a.flags + bq * 16;
  int* cntA = a.flags + 128 + bq * 16;
  int* genB = a.flags + 256 + bq * 16;
  int* cntB = a.flags + 384 + bq * 16;

  // weight row pointers (fixed over t)
  const bf16* bih = hwih_l + (size_t)(wid * 256 + s16 * 16 + l15) * 2048 + 1024; // h-part
  const bf16* bhh = hwhh_l + (size_t)(wid * 256 + s16 * 16 + l15) * 256;
  const bf16* rrow[4];
#pragma unroll
  for (int nt = 0; nt < 4; ++nt)
    rrow[nt] = whh_l + (size_t)(wid * 1024 + s16 * 64 + nt * 16 + l15) * 1024;
  const bf16* zrow[12];
#pragma unroll
  for (int j = 0; j < 12; ++j) {
    int ng = wid * 12 + j, tau = ng >> 4;
    const bf16* base = (tau == 0) ? a.w_zh : (tau == 1) ? a.w_zx : a.w_zb;
    zrow[j] = base + ((size_t)layer * 256 + (ng & 15) * 16 + l15) * 256;
  }
  const bf16* bzh_l = a.b_zh + layer * 256;
  const bf16* bzx_l = a.b_zx + layer * 256;
  const size_t wdo = ((size_t)(layer * 4 + wid) * 1024 + s16 * 64 + lane) * 64;
  const bf16 *pdh = a.w_dh + wdo, *pdx = a.w_dx + wdo, *pdb = a.w_db + wdo;

  float c_reg = 0.0f;    // main c for (batch tid>>6, h = s16*64 + (tid&63))
  float hc_reg = 0.0f;   // tid<64: hyper c for (batch tid>>4, dim s16*16 + (tid&15))

  for (int i = tid; i < 4 * 264; i += 256) ((bf16*)hh2A)[i] = (bf16)0.0f;
  __syncthreads();

  for (int t = 0; t < 256; ++t) {
    // ---- sync A: wait h(t) published by whole group (t=0 trivially passes) ----
    if (tid == 0) { while (ildi(genA) < t) __builtin_amdgcn_s_sleep(2); }
    __syncthreads();
    for (int i = tid; i < 1024; i += 256) {        // stage h(t): 4 x 256 u64
      int b = i >> 8, u = i & 255;
      *(u64*)&hA4[b][u * 4] = uld(a.hpub + ((size_t)(bq * 4 + b) << 8) + u);
    }
    __syncthreads();

    // ---- hg slice: wave g computes hg[g][4b][16d] (k = 1024 h + 256 hh_prev) ----
    {
      f32x4 cA = {};
      for (int kk = 0; kk < 1024; kk += 32) {
        int ko = kk + q * 8;
        bf16x8 bv = *(const bf16x8*)(bih + ko);
        bf16x8 av = *(const bf16x8*)&hA4[l15 & 3][ko];
        cA = mfma16(av, bv, cA);
      }
      for (int kk = 0; kk < 256; kk += 32) {
        int ko = kk + q * 8;
        bf16x8 bv = *(const bf16x8*)(bhh + ko);
        bf16x8 av = *(const bf16x8*)&hh2A[l15 & 3][ko];   // hh2(t-1)
        cA = mfma16(av, bv, cA);
      }
      if (lane < 16) {
#pragma unroll
        for (int r = 0; r < 4; ++r) hgs4[wid][r][lane] = cA[r];
      }
    }
    __syncthreads();

    // ---- hyper cell on own 16 dims (hc in registers, block-private) ----
    if (tid < 64) {
      int b = tid >> 4, dL = tid & 15;
      int dd = s16 * 16 + dL;
      const float* hxr = a.Hxp + ((size_t)(bq * 4 + b) * 256 + t) * 1024 + dd;
      float hi  = hgs4[0][b][dL] + (float)hybl[dd]       + hxr[0];
      float hf  = hgs4[1][b][dL] + (float)hybl[256 + dd] + hxr[256];
      float hgv = hgs4[2][b][dL] + (float)hybl[512 + dd] + hxr[512];
      float ho  = hgs4[3][b][dL] + (float)hybl[768 + dd] + hxr[768];
      hc_reg = sigf(hf) * hc_reg + sigf(hi) * tanhf_fast(hgv);
      hh2tmp[b][dL] = (bf16)(sigf(ho) * tanhf_fast(hc_reg));
    }
    __syncthreads();

    // ---- publish hh2 slice + arrive sync B ----
    if (tid < 16) {
      int b = tid >> 2, jj = tid & 3;
      u64 pk = *(const u64*)&hh2tmp[b][jj * 4];
      ust(a.hhpub + ((size_t)(bq * 4 + b) << 6) + s16 * 4 + jj, pk);
    }
    __builtin_amdgcn_s_waitcnt(0);
    __syncthreads();
    if (tid == 0) {
      int old = __hip_atomic_fetch_add(cntB, 1, __ATOMIC_RELAXED, SCOPE_AGENT);
      if (old == 16 * (t + 1) - 1) isti(genB, t + 1);
    }

    // ---- Rh (own gate slice, overlaps peers' hh2 publish) ----
    {
      f32x4 racc[4] = {};
      for (int kk = 0; kk < 1024; kk += 32) {
        const int ko = kk + q * 8;
        bf16x8 av = *(const bf16x8*)&hA4[l15 & 3][ko];
#pragma unroll
        for (int nt = 0; nt < 4; ++nt) {
          bf16x8 bv = *(const bf16x8*)(rrow[nt] + ko);
          racc[nt] = mfma16(av, bv, racc[nt]);
        }
      }
      if (lane < 16) {
#pragma unroll
        for (int nt = 0; nt < 4; ++nt)
#pragma unroll
          for (int r = 0; r < 4; ++r)
            RhL[r][wid * 64 + nt * 16 + lane] = racc[nt][r];
      }
    }

    // ---- sync B: wait full hh2(t), stage into hh2A ----
    if (tid == 0) { while (ildi(genB) < t + 1) __builtin_amdgcn_s_sleep(2); }
    __syncthreads();
    {
      int b = tid >> 6, u = tid & 63;
      *(u64*)&hh2A[b][u * 4] = uld(a.hhpub + ((size_t)(bq * 4 + b) << 6) + u);
    }
    __syncthreads();

    // ---- z = hh2 @ wz^T (+bias) ----
    {
      f32x4 zacc[12] = {};
      for (int kk = 0; kk < 256; kk += 32) {
        const int ko = kk + q * 8;
        bf16x8 av = *(const bf16x8*)&hh2A[l15 & 3][ko];
#pragma unroll
        for (int j = 0; j < 12; ++j) {
          bf16x8 bv = *(const bf16x8*)(zrow[j] + ko);
          zacc[j] = mfma16(av, bv, zacc[j]);
        }
      }
      if (lane < 16) {
#pragma unroll
        for (int j = 0; j < 12; ++j) {
          int ng = wid * 12 + j, tau = ng >> 4, col = (ng & 15) * 16 + lane;
          float bias = (tau == 0) ? (float)bzh_l[col] : (tau == 1) ? (float)bzx_l[col] : 0.0f;
#pragma unroll
          for (int r = 0; r < 4; ++r) zsL[r][tau * 256 + col] = zacc[j][r] + bias;
        }
      }
    }
    __syncthreads();

    // ---- d-projections + pre ----
    {
      float dH[4] = {}, dX[4] = {}, dB[4] = {};
      for (int e0 = 0; e0 < 64; e0 += 4) {
        bf16x4 wh = *(const bf16x4*)(pdh + e0);
        bf16x4 wx = *(const bf16x4*)(pdx + e0);
        bf16x4 wb = *(const bf16x4*)(pdb + e0);
        f32x4 zh_[4], zx_[4], zb_[4];
#pragma unroll
        for (int b = 0; b < 4; ++b) {
          zh_[b] = *(const f32x4*)&zsL[b][wid * 64 + e0];
          zx_[b] = *(const f32x4*)&zsL[b][256 + wid * 64 + e0];
          zb_[b] = *(const f32x4*)&zsL[b][512 + wid * 64 + e0];
        }
#pragma unroll
        for (int jj = 0; jj < 4; ++jj) {
          float whf = (float)wh[jj], wxf = (float)wx[jj], wbf = (float)wb[jj];
#pragma unroll
          for (int b = 0; b < 4; ++b) {
            dH[b] += zh_[b][jj] * whf;
            dX[b] += zx_[b][jj] * wxf;
            dB[b] += zb_[b][jj] * wbf;
          }
        }
      }
#pragma unroll
      for (int b = 0; b < 4; ++b) {
        float rh = RhL[b][wid * 64 + lane];
        float xp = (float)a.Xp[((size_t)(bq * 4 + b) * 256 + t) * 4096 + wid * 1024 + s16 * 64 + lane];
        float b0v = (float)b0_l[wid * 1024 + s16 * 64 + lane];
        presL[b][wid * 64 + lane] = dH[b] * rh + dX[b] * xp + dB[b] + b0v;
      }
    }
    __syncthreads();

    // ---- main cell + outputs ----
    {
      const int cb = tid >> 6, chl = tid & 63;
      float iv = presL[cb][chl];
      float fv = presL[cb][64 + chl];
      float gv = presL[cb][128 + chl];
      float ov = presL[cb][192 + chl];
      c_reg = sigf(fv) * c_reg + sigf(iv) * tanhf_fast(gv);
      float hn = sigf(ov) * tanhf_fast(c_reg);
      hbuf[cb][chl] = (bf16)hn;
      const size_t oo = ((size_t)(bq * 4 + cb) * 256 + t) * 1024 + s16 * 64 + chl;
      if (layer == 0) a.Y0[oo] = (bf16)hn;
      else {
        a.outp[oo] = hn;
        if (t == 255) {
          a.outp[8388608 + (bq * 4 + cb) * 1024 + s16 * 64 + chl] = hn;
          a.outp[8421376 + (bq * 4 + cb) * 1024 + s16 * 64 + chl] = c_reg;
        }
      }
    }
    __syncthreads();

    // ---- publish own h slice + arrive sync A(t+1) ----
    if (tid < 64) {
      int b = tid >> 4, u = tid & 15;
      u64 pk = *(const u64*)&hbuf[b][u * 4];
      ust(a.hpub + ((size_t)(bq * 4 + b) << 8) + s16 * 16 + u, pk);
    }
    __builtin_amdgcn_s_waitcnt(0);
    __syncthreads();
    if (tid == 0) {
      int old = __hip_atomic_fetch_add(cntA, 1, __ATOMIC_RELAXED, SCOPE_AGENT);
      if (old == 16 * (t + 1) - 1) isti(genA, t + 1);
    }
  }
}

extern "C" void kernel_launch(void* const* d_in, const int* in_sizes, int n_in,
                              void* d_out, int out_size, void* d_ws, size_t ws_size,
                              hipStream_t stream) {
  float* outp = (float*)d_out;
  char* ws = (char*)d_ws;
  bf16*  Xp     = (bf16*) (ws);                      // 67,108,864
  float* Hxp    = (float*)(ws + 67108864ull);        // 33,554,432
  bf16*  Y0     = (bf16*) (ws + 100663296ull);       // 16,777,216
  u64*   hpub   = (u64*)  (ws + 117440512ull);       //     65,536
  u64*   hhpub  = (u64*)  (ws + 117506048ull);       //     16,384
  int*   flags  = (int*)  (ws + 117653504ull);       //     16,384
  bf16* c_input = (bf16*)(ws + 117669888ull);        // 16,777,216
  bf16* c_w_ih  = (bf16*)(ws + 134447104ull);        // 16,777,216
  bf16* c_w_hh  = (bf16*)(ws + 151224320ull);        // 16,777,216
  bf16* c_hwih  = (bf16*)(ws + 168001536ull);        //  8,388,608
  bf16* c_hwhh  = (bf16*)(ws + 176390144ull);        //  1,048,576
  bf16* c_hyb   = (bf16*)(ws + 177438720ull);        //      4,096
  bf16* c_wzh   = (bf16*)(ws + 177442816ull);        //    262,144
  bf16* c_bzh   = (bf16*)(ws + 177704960ull);        //      1,024
  bf16* c_wzx   = (bf16*)(ws + 177705984ull);        //    262,144
  bf16* c_bzx   = (bf16*)(ws + 177968128ull);        //      1,024
  bf16* c_wzb   = (bf16*)(ws + 177969152ull);        //    262,144
  bf16* c_wdh   = (bf16*)(ws + 178231296ull);        //  1,048,576
  bf16* c_wdx   = (bf16*)(ws + 179279872ull);        //  1,048,576
  bf16* c_wdb   = (bf16*)(ws + 180328448ull);        //  1,048,576
  bf16* c_b0    = (bf16*)(ws + 181377024ull);        //     16,384
  int*  dflag   = (int*) (ws + 181393408ull);        //          4

  hipLaunchKernelGGL(detect_kernel, dim3(1), dim3(256), 0, stream, d_in[2], dflag);
  CvtSrc S; CvtDst D;
  for (int i = 0; i < 15; ++i) S.s[i] = d_in[i];
  D.d[0] = c_input; D.d[1] = c_w_ih; D.d[2] = c_w_hh; D.d[3] = c_hwih; D.d[4] = c_hwhh;
  D.d[5] = c_hyb;   D.d[6] = c_wzh;  D.d[7] = c_bzh;  D.d[8] = c_wzx;  D.d[9] = c_bzx;
  D.d[10] = c_wzb;  D.d[11] = c_wdh; D.d[12] = c_wdx; D.d[13] = c_wdb; D.d[14] = c_b0;
  hipLaunchKernelGGL(convert_kernel, dim3(2048), dim3(256), 0, stream, S, D, dflag);

  for (int layer = 0; layer < 2; ++layer) {
    hipLaunchKernelGGL(init_kernel, dim3(32), dim3(256), 0, stream, hpub, hhpub, flags);
    const bf16* A = (layer == 0) ? c_input : Y0;
    hipLaunchKernelGGL(gemm_pre, dim3(10240), dim3(256), 0, stream,
                       A, c_w_ih + (size_t)layer * 4096 * 1024,
                       c_hwih + (size_t)layer * 1024 * 2048, Xp, Hxp);
    SeqArgs sa;
    sa.layer = layer;
    sa.w_hh = c_w_hh; sa.hwih = c_hwih; sa.hwhh = c_hwhh; sa.hyb = c_hyb;
    sa.w_zh = c_wzh; sa.b_zh = c_bzh; sa.w_zx = c_wzx; sa.b_zx = c_bzx; sa.w_zb = c_wzb;
    sa.w_dh = c_wdh; sa.w_dx = c_wdx; sa.w_db = c_wdb; sa.b0 = c_b0;
    sa.Xp = Xp; sa.Hxp = Hxp;
    sa.hpub = hpub; sa.hhpub = hhpub;
    sa.Y0 = Y0; sa.outp = outp;
    sa.flags = flags;
    hipLaunchKernelGGL(seq_kernel, dim3(128), dim3(256), 0, stream, sa);
  }
}